// Round 2
// baseline (150.386 us; speedup 1.0000x reference)
//
#include <hip/hip_runtime.h>
#include <math.h>

#define IMG_H 512
#define IMG_W 512
#define NSLOT 64
#define HT_S  56      // hT stride in halves: 112 B rows, 16B-aligned

typedef _Float16 f16x4 __attribute__((ext_vector_type(4)));
typedef _Float16 f16x8 __attribute__((ext_vector_type(8)));
typedef float    f32x4 __attribute__((ext_vector_type(4)));

// Zero-padded 11-tap Gaussian (sigma=1.5), f16, normalized (1/sum = 0.26601173).
// Index domain: idx in [-18, 33] -> WPAD[idx + 18]. Nonzero only for idx in [0,10].
__device__ const _Float16 WPAD[52] = {
    (_Float16)0.f,(_Float16)0.f,(_Float16)0.f,(_Float16)0.f,(_Float16)0.f,(_Float16)0.f,
    (_Float16)0.f,(_Float16)0.f,(_Float16)0.f,(_Float16)0.f,(_Float16)0.f,(_Float16)0.f,
    (_Float16)0.f,(_Float16)0.f,(_Float16)0.f,(_Float16)0.f,(_Float16)0.f,(_Float16)0.f,   // idx -18..-1
    (_Float16)0.00102838f, (_Float16)0.00759876f, (_Float16)0.03600077f,
    (_Float16)0.10936065f, (_Float16)0.21300554f, (_Float16)0.26601173f,
    (_Float16)0.21300554f, (_Float16)0.10936065f, (_Float16)0.03600077f,
    (_Float16)0.00759876f, (_Float16)0.00102838f,                                          // idx 0..10
    (_Float16)0.f,(_Float16)0.f,(_Float16)0.f,(_Float16)0.f,(_Float16)0.f,(_Float16)0.f,
    (_Float16)0.f,(_Float16)0.f,(_Float16)0.f,(_Float16)0.f,(_Float16)0.f,(_Float16)0.f,
    (_Float16)0.f,(_Float16)0.f,(_Float16)0.f,(_Float16)0.f,(_Float16)0.f,(_Float16)0.f,
    (_Float16)0.f,(_Float16)0.f,(_Float16)0.f,(_Float16)0.f,(_Float16)0.f                  // idx 11..33
};

// 8 consecutive f16 table entries starting at (padded) index `base`.
__device__ __forceinline__ f16x8 frag_from_tab(int base)
{
    f16x8 f;
    #pragma unroll
    for (int j = 0; j < 8; ++j) f[j] = WPAD[base + j];
    return f;
}

__global__ __launch_bounds__(256, 6)
void ssim_main(const float* __restrict__ pred, const float* __restrict__ targ,
               float* __restrict__ partial, double* __restrict__ acc, int mode)
{
    __shared__ _Float16 hT[4][32][HT_S];     // [q][out_col][halo_row 0..47]

    const int tid  = threadIdx.x;
    const int lane = tid & 63, wave = tid >> 6;
    const int ln   = lane & 15, lg = lane >> 4;

    // XCD swizzle: 8 XCDs, grid % 8 == 0 (nwg = n_img*256). Give each XCD a
    // contiguous chunk (= whole image planes) so halo re-reads stay in one L2.
    const int bid   = ((blockIdx.z << 4) + blockIdx.y) * 16 + blockIdx.x;
    const int chunk = (int)gridDim.z << 5;            // nwg/8 = n_img*256/8
    const int nb    = (bid & 7) * chunk + (bid >> 3);
    const int img   = nb >> 8;
    const int rem   = nb & 255;
    const int ty    = rem >> 4, tx = rem & 15;

    const float* __restrict__ p = pred + (size_t)img * (IMG_H * IMG_W);
    const float* __restrict__ t = targ + (size_t)img * (IMG_H * IMG_W);
    const int gr0 = ty * 32 - 5;       // halo row 0 (global)
    const int wo  = tx * 32 - 8;       // halo col 0 (global)

    // Bw:  B[k][n] = w[k-n-3]  -> WPAD[18 + lg*8+j - ln - 3]
    const f16x8 Bw = frag_from_tab(15 + lg * 8 - ln);
    const f32x4 z = {0.f, 0.f, 0.f, 0.f};

    // ---- Phase 1: issue ALL global loads (branch-free, clamped + masked) ----
    // Tile A: wave w -> tile w (rt = w>>1, ct = w&1).
    const int rtA = wave >> 1, ctA = wave & 1;
    const int grA = gr0 + rtA * 16 + ln;
    const int gcA = wo + ctA * 16 + lg * 8;
    const bool inA = ((unsigned)grA < (unsigned)IMG_H) &&
                     !(tx == 0 && ctA == 0 && lg == 0) &&
                     !(tx == 15 && ctA == 1 && lg == 3);
    const int grAc = grA < 0 ? 0 : (grA > IMG_H - 1 ? IMG_H - 1 : grA);
    const int gcAc = gcA < 0 ? 0 : (gcA > IMG_W - 8 ? IMG_W - 8 : gcA);
    const float* bpA = p + (size_t)grAc * IMG_W + gcAc;
    const float* btA = t + (size_t)grAc * IMG_W + gcAc;
    float4 pA0 = ((const float4*)bpA)[0], pA1 = ((const float4*)bpA)[1];
    float4 tA0 = ((const float4*)btA)[0], tA1 = ((const float4*)btA)[1];

    // Tile B: waves 0,1 also do tile wave+4 (rt = 2, ct = wave). Scalar branch.
    float4 pB0{}, pB1{}, tB0{}, tB1{};
    bool inB = false;
    if (wave < 2) {
        const int ctB = wave;
        const int grB = gr0 + 32 + ln;
        const int gcB = wo + ctB * 16 + lg * 8;
        inB = ((unsigned)grB < (unsigned)IMG_H) &&
              !(tx == 0 && ctB == 0 && lg == 0) &&
              !(tx == 15 && ctB == 1 && lg == 3);
        const int grBc = grB < 0 ? 0 : (grB > IMG_H - 1 ? IMG_H - 1 : grB);
        const int gcBc = gcB < 0 ? 0 : (gcB > IMG_W - 8 ? IMG_W - 8 : gcB);
        const float* bpB = p + (size_t)grBc * IMG_W + gcBc;
        const float* btB = t + (size_t)grBc * IMG_W + gcBc;
        pB0 = ((const float4*)bpB)[0]; pB1 = ((const float4*)bpB)[1];
        tB0 = ((const float4*)btB)[0]; tB1 = ((const float4*)btB)[1];
    }

    // A2w: A[m][k] = w[k-m] -> WPAD[18 + lg*8+j - ln]; issue before conversions
    // so its loads overlap the pixel-load waits.
    const f16x8 A2w = frag_from_tab(18 + lg * 8 - ln);

    // ---- Phase 2: convert + horizontal MFMA on {s, d, s^2, d^2} ----
    auto conv_tile = [&](const float4& a0, const float4& a1,
                         const float4& b0, const float4& b1,
                         bool in, int ocol, int orow) {
        const _Float16 mh = in ? (_Float16)1.0f : (_Float16)0.0f;
        const f16x8 mv = {mh, mh, mh, mh, mh, mh, mh, mh};
        f16x8 s8 = f16x8{
            (_Float16)(a0.x + b0.x), (_Float16)(a0.y + b0.y),
            (_Float16)(a0.z + b0.z), (_Float16)(a0.w + b0.w),
            (_Float16)(a1.x + b1.x), (_Float16)(a1.y + b1.y),
            (_Float16)(a1.z + b1.z), (_Float16)(a1.w + b1.w)} * mv;
        f16x8 d8 = f16x8{
            (_Float16)(a0.x - b0.x), (_Float16)(a0.y - b0.y),
            (_Float16)(a0.z - b0.z), (_Float16)(a0.w - b0.w),
            (_Float16)(a1.x - b1.x), (_Float16)(a1.y - b1.y),
            (_Float16)(a1.z - b1.z), (_Float16)(a1.w - b1.w)} * mv;
        f16x8 fq[4];
        fq[0] = s8; fq[1] = d8;
        fq[2] = s8 * s8; fq[3] = d8 * d8;
        #pragma unroll
        for (int q = 0; q < 4; ++q) {
            f32x4 dd = __builtin_amdgcn_mfma_f32_16x16x32_f16(fq[q], Bw, z, 0, 0, 0);
            *(f16x4*)&hT[q][ocol][orow] =
                f16x4{(_Float16)dd[0], (_Float16)dd[1], (_Float16)dd[2], (_Float16)dd[3]};
        }
    };
    conv_tile(pA0, pA1, tA0, tA1, inA, ctA * 16 + ln, rtA * 16 + lg * 4);
    if (wave < 2)
        conv_tile(pB0, pB1, tB0, tB1, inB, wave * 16 + ln, 32 + lg * 4);
    __syncthreads();

    // ---- Stage C: vertical conv via MFMA (weights as A) + SSIM ----
    float lsum = 0.f;
    {
        const int ctv = wave & 1, rtv = wave >> 1;   // one 16x16 output tile per wave
        const int ocol  = ctv * 16 + ln;
        const int rbase = rtv * 16 + lg * 8;         // 16B-aligned b128 reads
        f32x4 accq[4];
        #pragma unroll
        for (int q = 0; q < 4; ++q) {
            f16x8 b = *(const f16x8*)&hT[q][ocol][rbase];
            accq[q] = __builtin_amdgcn_mfma_f32_16x16x32_f16(A2w, b, z, 0, 0, 0);
        }
        // F1=conv(s)=mp+mt, F2=conv(d)=mp-mt, F3=conv(s^2), F4=conv(d^2)
        const float C1 = 1e-4f, C2 = 9e-4f;
        #pragma unroll
        for (int r = 0; r < 4; ++r) {
            float F1 = accq[0][r], F2 = accq[1][r];
            float F3 = accq[2][r], F4 = accq[3][r];
            float a = F1 * F1, b = F2 * F2;
            float mpmt2 = 0.5f * (a - b);            // 2*mp*mt
            float msq   = 0.5f * (a + b);            // mp^2 + mt^2
            float cpt2  = 0.5f * (F3 - F4) - mpmt2;  // 2*sigma_pt
            float vsum  = 0.5f * (F3 + F4) - msq;    // sigma_p^2 + sigma_t^2
            float num = (mpmt2 + C1) * (cpt2 + C2);
            float den = (msq + C1) * (vsum + C2);
            lsum = fmaf(num, __builtin_amdgcn_rcpf(den), lsum);
        }
    }

    // ---- wave reduce -> per-wave slot (mode 0) or atomic (mode 1); no end barrier ----
    #pragma unroll
    for (int off = 32; off > 0; off >>= 1)
        lsum += __shfl_down(lsum, off, 64);
    if (lane == 0) {
        if (mode == 0) partial[nb * 4 + wave] = lsum;
        else atomicAdd(&acc[(nb * 4 + wave) & (NSLOT - 1)], (double)lsum);
    }
}

__global__ void ssim_init(double* acc)
{
    if (threadIdx.x < NSLOT) acc[threadIdx.x] = 0.0;
}

__global__ __launch_bounds__(1024)
void ssim_fin_slots(const float* __restrict__ partial, float* __restrict__ out,
                    int n4, double inv_n)
{
    __shared__ double red[16];
    double s = 0.0;
    const int tid = threadIdx.x;
    for (int i = tid; i < n4; i += 1024) {
        float4 v = ((const float4*)partial)[i];
        s += (double)v.x + (double)v.y + (double)v.z + (double)v.w;
    }
    #pragma unroll
    for (int off = 32; off > 0; off >>= 1)
        s += __shfl_down(s, off, 64);
    if ((tid & 63) == 0) red[tid >> 6] = s;
    __syncthreads();
    if (tid == 0) {
        double tot = 0.0;
        #pragma unroll
        for (int w = 0; w < 16; ++w) tot += red[w];
        out[0] = (float)(1.0 - tot * inv_n);
    }
}

__global__ void ssim_fin_atomic(const double* __restrict__ acc, float* __restrict__ out,
                                double inv_n)
{
    if (threadIdx.x == 0) {
        double s = 0.0;
        for (int i = 0; i < NSLOT; ++i) s += acc[i];
        out[0] = (float)(1.0 - s * inv_n);
    }
}

extern "C" void kernel_launch(void* const* d_in, const int* in_sizes, int n_in,
                              void* d_out, int out_size, void* d_ws, size_t ws_size,
                              hipStream_t stream)
{
    const float* pred = (const float*)d_in[0];
    const float* targ = (const float*)d_in[1];
    float* out = (float*)d_out;

    const long long total = (long long)in_sizes[0];       // 16*3*512*512
    const int n_img = (int)(total / (IMG_H * IMG_W));     // 48 planes
    dim3 grid(IMG_W / 32, IMG_H / 32, n_img);
    const int nblk = grid.x * grid.y * grid.z;
    const int nslots = nblk * 4;
    const double inv_n = 1.0 / (double)total;

    if (ws_size >= (size_t)nslots * sizeof(float)) {
        float* partial = (float*)d_ws;
        hipLaunchKernelGGL(ssim_main, grid, dim3(256), 0, stream,
                           pred, targ, partial, (double*)nullptr, 0);
        hipLaunchKernelGGL(ssim_fin_slots, dim3(1), dim3(1024), 0, stream,
                           partial, out, nslots / 4, inv_n);
    } else {
        double* acc = (double*)d_ws;
        hipLaunchKernelGGL(ssim_init, dim3(1), dim3(64), 0, stream, acc);
        hipLaunchKernelGGL(ssim_main, grid, dim3(256), 0, stream,
                           pred, targ, (float*)nullptr, acc, 1);
        hipLaunchKernelGGL(ssim_fin_atomic, dim3(1), dim3(1), 0, stream,
                           acc, out, inv_n);
    }
}

// Round 3
// 141.071 us; speedup vs baseline: 1.0660x; 1.0660x over previous
//
#include <hip/hip_runtime.h>
#include <math.h>

#define IMG_H 512
#define IMG_W 512
#define NSLOT 64

typedef _Float16 f16x4 __attribute__((ext_vector_type(4)));
typedef _Float16 f16x8 __attribute__((ext_vector_type(8)));
typedef float    f32x4 __attribute__((ext_vector_type(4)));

// Zero-padded 11-tap Gaussian (sigma=1.5), f16, normalized (1/sum = 0.26601173).
// Index domain: idx in [-18, 33] -> WPAD[idx + 18]. Nonzero only for idx in [0,10].
__device__ const _Float16 WPAD[52] = {
    (_Float16)0.f,(_Float16)0.f,(_Float16)0.f,(_Float16)0.f,(_Float16)0.f,(_Float16)0.f,
    (_Float16)0.f,(_Float16)0.f,(_Float16)0.f,(_Float16)0.f,(_Float16)0.f,(_Float16)0.f,
    (_Float16)0.f,(_Float16)0.f,(_Float16)0.f,(_Float16)0.f,(_Float16)0.f,(_Float16)0.f,   // idx -18..-1
    (_Float16)0.00102838f, (_Float16)0.00759876f, (_Float16)0.03600077f,
    (_Float16)0.10936065f, (_Float16)0.21300554f, (_Float16)0.26601173f,
    (_Float16)0.21300554f, (_Float16)0.10936065f, (_Float16)0.03600077f,
    (_Float16)0.00759876f, (_Float16)0.00102838f,                                          // idx 0..10
    (_Float16)0.f,(_Float16)0.f,(_Float16)0.f,(_Float16)0.f,(_Float16)0.f,(_Float16)0.f,
    (_Float16)0.f,(_Float16)0.f,(_Float16)0.f,(_Float16)0.f,(_Float16)0.f,(_Float16)0.f,
    (_Float16)0.f,(_Float16)0.f,(_Float16)0.f,(_Float16)0.f,(_Float16)0.f,(_Float16)0.f,
    (_Float16)0.f,(_Float16)0.f,(_Float16)0.f,(_Float16)0.f,(_Float16)0.f                  // idx 11..33
};

__device__ __forceinline__ f16x8 frag_from_tab(int base)
{
    f16x8 f;
    #pragma unroll
    for (int j = 0; j < 8; ++j) f[j] = WPAD[base + j];
    return f;
}

// Per-wave-private transpose buffer: [wave][q][out_col][halo_row 0..47], f16.
// Row pitch 96 B (multiple of 16 B -> b128 reads legal). 16-byte XOR swizzle
// on the row-offset (addr ^= (ln&4)<<2), same involution for write and read,
// spreads the 16 column-lanes across 8 distinct bank starts.
#define HT_BYTES (4 * 4 * 16 * 48 * 2)   // 24576 B -> 6 blocks/CU

__global__ __launch_bounds__(256, 6)
void ssim_main(const float* __restrict__ pred, const float* __restrict__ targ,
               float* __restrict__ partial, double* __restrict__ acc, int mode)
{
    __shared__ __align__(128) _Float16 hT[4][4][16][48];

    const int tid  = threadIdx.x;
    const int lane = tid & 63, wave = tid >> 6;
    const int ln   = lane & 15, lg = lane >> 4;

    // XCD swizzle: 8 XCDs, nwg = 8*16*n_img (multiple of 8). Contiguous chunk
    // (= whole image planes) per XCD for L2/L3 locality.
    const int bid   = ((blockIdx.z * 16 + blockIdx.y) * 8) + blockIdx.x;
    const int chunk = (int)gridDim.z << 4;            // 16 * n_img = nwg/8
    const int nb    = (bid & 7) * chunk + (bid >> 3);
    const int img   = nb >> 7;                        // 128 blocks per plane
    const int rem   = nb & 127;
    const int ty    = rem >> 3, tx = rem & 7;

    const float* __restrict__ p = pred + (size_t)img * (IMG_H * IMG_W);
    const float* __restrict__ t = targ + (size_t)img * (IMG_H * IMG_W);

    // Wave-private region: output rows ty*32..+31, cols tx*64 + wave*16 ..+15.
    const int gr0 = ty * 32 - 5;                      // halo row 0 (48 rows)
    const int wo  = tx * 64 + wave * 16 - 8;          // halo col 0 (32 cols)

    // Banded Gaussian fragments:
    // Bw (B-op, horiz):  B[k][n] = w[k-n-3] -> WPAD[15 + lg*8+j - ln]
    // A2w (A-op, vert):  A[m][k] = w[k-m]   -> WPAD[18 + lg*8+j - ln]
    const f16x8 Bw  = frag_from_tab(15 + lg * 8 - ln);
    const f16x8 A2w = frag_from_tab(18 + lg * 8 - ln);
    const f32x4 z = {0.f, 0.f, 0.f, 0.f};

    // Column (per-lane, uniform across tiles): 8 cols at wo + lg*8.
    const int  gc    = wo + lg * 8;
    const bool colOK = (gc >= 0) && (gc <= IMG_W - 8);
    const int  gcc   = gc < 0 ? 0 : (gc > IMG_W - 8 ? IMG_W - 8 : gc);

    // Per-tile rows (A-frag row = ln).
    int  grr[3]; bool ok[3];
    const float *bp[3], *bt[3];
    #pragma unroll
    for (int rt = 0; rt < 3; ++rt) {
        const int gr = gr0 + rt * 16 + ln;
        ok[rt] = ((unsigned)gr < (unsigned)IMG_H) && colOK;
        const int grc = gr < 0 ? 0 : (gr > IMG_H - 1 ? IMG_H - 1 : gr);
        grr[rt] = grc;
        bp[rt] = p + (size_t)grc * IMG_W + gcc;
        bt[rt] = t + (size_t)grc * IMG_W + gcc;
    }

    const int swz = (ln & 4) << 2;    // 16-byte XOR swizzle bit

    // Horizontal conv of one 16-row tile: pixels -> {s,d,s^2,d^2} frags -> MFMA -> hT.
    auto proc = [&](int rt, float4 a0, float4 a1, float4 b0, float4 b1, bool in) {
        const _Float16 mh = in ? (_Float16)1.0f : (_Float16)0.0f;
        const f16x8 mv = {mh, mh, mh, mh, mh, mh, mh, mh};
        f16x8 s8 = f16x8{
            (_Float16)(a0.x + b0.x), (_Float16)(a0.y + b0.y),
            (_Float16)(a0.z + b0.z), (_Float16)(a0.w + b0.w),
            (_Float16)(a1.x + b1.x), (_Float16)(a1.y + b1.y),
            (_Float16)(a1.z + b1.z), (_Float16)(a1.w + b1.w)} * mv;
        f16x8 d8 = f16x8{
            (_Float16)(a0.x - b0.x), (_Float16)(a0.y - b0.y),
            (_Float16)(a0.z - b0.z), (_Float16)(a0.w - b0.w),
            (_Float16)(a1.x - b1.x), (_Float16)(a1.y - b1.y),
            (_Float16)(a1.z - b1.z), (_Float16)(a1.w - b1.w)} * mv;
        f16x8 fq[4];
        fq[0] = s8; fq[1] = d8;
        fq[2] = s8 * s8; fq[3] = d8 * d8;
        const int woff = ((rt * 16 + lg * 4) * 2) ^ swz;   // b64, 8B-aligned
        #pragma unroll
        for (int q = 0; q < 4; ++q) {
            f32x4 dd = __builtin_amdgcn_mfma_f32_16x16x32_f16(fq[q], Bw, z, 0, 0, 0);
            *(f16x4*)((char*)&hT[wave][q][ln][0] + woff) =
                f16x4{(_Float16)dd[0], (_Float16)dd[1], (_Float16)dd[2], (_Float16)dd[3]};
        }
    };

    // Stage B: issue loads for tiles 0,1; process 0; issue tile 2; process 1,2.
    float4 a00 = ((const float4*)bp[0])[0], a01 = ((const float4*)bp[0])[1];
    float4 b00 = ((const float4*)bt[0])[0], b01 = ((const float4*)bt[0])[1];
    float4 a10 = ((const float4*)bp[1])[0], a11 = ((const float4*)bp[1])[1];
    float4 b10 = ((const float4*)bt[1])[0], b11 = ((const float4*)bt[1])[1];
    proc(0, a00, a01, b00, b01, ok[0]);
    float4 a20 = ((const float4*)bp[2])[0], a21 = ((const float4*)bp[2])[1];
    float4 b20 = ((const float4*)bt[2])[0], b21 = ((const float4*)bt[2])[1];
    proc(1, a10, a11, b10, b11, ok[1]);
    proc(2, a20, a21, b20, b21, ok[2]);

    // Same-wave LDS write->read ordering: drain lgkm, then fence the scheduler
    // (rule 18: compiler may otherwise hoist reads past the inline-asm wait).
    asm volatile("s_waitcnt lgkmcnt(0)" ::: "memory");
    __builtin_amdgcn_sched_barrier(0);

    // Stage C: vertical conv (weights as A) + SSIM. Two 16-row output tiles.
    float lsum = 0.f;
    const float C1 = 1e-4f, C2 = 9e-4f;
    #pragma unroll
    for (int v = 0; v < 2; ++v) {
        const int roff = ((v * 16 + lg * 8) * 2) ^ swz;    // b128, 16B-aligned
        f32x4 accq[4];
        #pragma unroll
        for (int q = 0; q < 4; ++q) {
            f16x8 b = *(const f16x8*)((char*)&hT[wave][q][ln][0] + roff);
            accq[q] = __builtin_amdgcn_mfma_f32_16x16x32_f16(A2w, b, z, 0, 0, 0);
        }
        #pragma unroll
        for (int r = 0; r < 4; ++r) {
            float F1 = accq[0][r], F2 = accq[1][r];
            float F3 = accq[2][r], F4 = accq[3][r];
            float a = F1 * F1, b = F2 * F2;
            float mpmt2 = 0.5f * (a - b);            // 2*mp*mt
            float msq   = 0.5f * (a + b);            // mp^2 + mt^2
            float cpt2  = 0.5f * (F3 - F4) - mpmt2;  // 2*sigma_pt
            float vsum  = 0.5f * (F3 + F4) - msq;    // sigma_p^2 + sigma_t^2
            float num = (mpmt2 + C1) * (cpt2 + C2);
            float den = (msq + C1) * (vsum + C2);
            lsum = fmaf(num, __builtin_amdgcn_rcpf(den), lsum);
        }
    }

    // Wave reduce -> per-wave slot (mode 0) or atomic (mode 1). No barriers.
    #pragma unroll
    for (int off = 32; off > 0; off >>= 1)
        lsum += __shfl_down(lsum, off, 64);
    if (lane == 0) {
        if (mode == 0) partial[nb * 4 + wave] = lsum;
        else atomicAdd(&acc[(nb * 4 + wave) & (NSLOT - 1)], (double)lsum);
    }
}

__global__ void ssim_init(double* acc)
{
    if (threadIdx.x < NSLOT) acc[threadIdx.x] = 0.0;
}

__global__ __launch_bounds__(1024)
void ssim_fin_slots(const float* __restrict__ partial, float* __restrict__ out,
                    int n4, double inv_n)
{
    __shared__ double red[16];
    double s = 0.0;
    const int tid = threadIdx.x;
    for (int i = tid; i < n4; i += 1024) {
        float4 v = ((const float4*)partial)[i];
        s += (double)v.x + (double)v.y + (double)v.z + (double)v.w;
    }
    #pragma unroll
    for (int off = 32; off > 0; off >>= 1)
        s += __shfl_down(s, off, 64);
    if ((tid & 63) == 0) red[tid >> 6] = s;
    __syncthreads();
    if (tid == 0) {
        double tot = 0.0;
        #pragma unroll
        for (int w = 0; w < 16; ++w) tot += red[w];
        out[0] = (float)(1.0 - tot * inv_n);
    }
}

__global__ void ssim_fin_atomic(const double* __restrict__ acc, float* __restrict__ out,
                                double inv_n)
{
    if (threadIdx.x == 0) {
        double s = 0.0;
        for (int i = 0; i < NSLOT; ++i) s += acc[i];
        out[0] = (float)(1.0 - s * inv_n);
    }
}

extern "C" void kernel_launch(void* const* d_in, const int* in_sizes, int n_in,
                              void* d_out, int out_size, void* d_ws, size_t ws_size,
                              hipStream_t stream)
{
    const float* pred = (const float*)d_in[0];
    const float* targ = (const float*)d_in[1];
    float* out = (float*)d_out;

    const long long total = (long long)in_sizes[0];       // 16*3*512*512
    const int n_img = (int)(total / (IMG_H * IMG_W));     // 48 planes
    dim3 grid(IMG_W / 64, IMG_H / 32, n_img);             // 8 x 16 x 48 = 6144
    const int nblk = grid.x * grid.y * grid.z;
    const int nslots = nblk * 4;
    const double inv_n = 1.0 / (double)total;

    if (ws_size >= (size_t)nslots * sizeof(float)) {
        float* partial = (float*)d_ws;
        hipLaunchKernelGGL(ssim_main, grid, dim3(256), 0, stream,
                           pred, targ, partial, (double*)nullptr, 0);
        hipLaunchKernelGGL(ssim_fin_slots, dim3(1), dim3(1024), 0, stream,
                           partial, out, nslots / 4, inv_n);
    } else {
        double* acc = (double*)d_ws;
        hipLaunchKernelGGL(ssim_init, dim3(1), dim3(64), 0, stream, acc);
        hipLaunchKernelGGL(ssim_main, grid, dim3(256), 0, stream,
                           pred, targ, (float*)nullptr, acc, 1);
        hipLaunchKernelGGL(ssim_fin_atomic, dim3(1), dim3(1), 0, stream,
                           acc, out, inv_n);
    }
}